// Round 6
// baseline (8840.753 us; speedup 1.0000x reference)
//
#include <hip/hip_runtime.h>
#include <hip/hip_bf16.h>
#include <stdint.h>

// ---------------------------------------------------------------------------
// GraphEncoder. Round 6: barrier-free per-batch scan (R5 topology) + explicit
// software pipelining: double-buffered register prefetch in all GEMV stages
// (vmcnt never drains to 0 mid-loop) and global_load_lds for mem staging.
// R5 post-mortem: 576 loads/thread/step x ~200cyc exposed = 47us/step; this
// round targets covering that latency with 10-20 loads in flight per wave.
// ---------------------------------------------------------------------------

typedef __bf16 bf16_t;
typedef __bf16 bf16x8 __attribute__((ext_vector_type(8)));
typedef float  f32x4  __attribute__((ext_vector_type(4)));
typedef _Float16 f16;
typedef _Float16 f16x2 __attribute__((ext_vector_type(2)));

#define MFMA16(a,b,c) __builtin_amdgcn_mfma_f32_16x16x32_bf16((a),(b),(c),0,0,0)

// ---- workspace layout (bytes) ----
static constexpr size_t OFF_MEM   = 0;                      // f16 [1536][64][512]
static constexpr size_t OFF_WALLT = 100663296;              // u32 [64][2560][4]
static constexpr size_t OFF_WCT   = OFF_WALLT + 2621440;    // u32 [64][512][4]
static constexpr size_t OFF_WIT   = OFF_WCT + 524288;       // u32 [64][1536][4]
static constexpr size_t OFF_LEN   = OFF_WIT + 1572864;      // int [1536]
static constexpr size_t WS_NEED   = OFF_LEN + 8192;         // 105,390,080

// ---- helpers ----
__device__ __forceinline__ float dot2(unsigned w, unsigned x, float acc) {
#if __has_builtin(__builtin_amdgcn_fdot2)
  return __builtin_amdgcn_fdot2(__builtin_bit_cast(f16x2, w),
                                __builtin_bit_cast(f16x2, x), acc, false);
#else
  f16x2 wv = __builtin_bit_cast(f16x2, w);
  f16x2 xv = __builtin_bit_cast(f16x2, x);
  return acc + (float)wv[0]*(float)xv[0] + (float)wv[1]*(float)xv[1];
#endif
}
__device__ __forceinline__ unsigned pack_h2(float a, float b) {
  f16 ha = (f16)a, hb = (f16)b;
  unsigned short ua = __builtin_bit_cast(unsigned short, ha);
  unsigned short ub = __builtin_bit_cast(unsigned short, hb);
  return (unsigned)ua | ((unsigned)ub << 16);
}
__device__ __forceinline__ bf16x8 cvt8(float4 lo, float4 hi) {
  bf16x8 v;
  v[0]=(__bf16)lo.x; v[1]=(__bf16)lo.y; v[2]=(__bf16)lo.z; v[3]=(__bf16)lo.w;
  v[4]=(__bf16)hi.x; v[5]=(__bf16)hi.y; v[6]=(__bf16)hi.z; v[7]=(__bf16)hi.w;
  return v;
}
__device__ __forceinline__ float fsig(float x) {
  return __builtin_amdgcn_rcpf(1.f + __expf(-x));
}
__device__ __forceinline__ float ftanh(float x) {
  float e = __expf(-2.f * fabsf(x));
  float t = (1.f - e) * __builtin_amdgcn_rcpf(1.f + e);
  return __builtin_copysignf(t, x);
}
// async global->LDS, 16B per lane (per-lane gptr; LDS dest contiguous in lane order)
__device__ __forceinline__ void load_lds16(const f16* g, f16* l) {
  __builtin_amdgcn_global_load_lds(
      (const __attribute__((address_space(1))) unsigned*)g,
      (__attribute__((address_space(3))) unsigned*)l, 16, 0, 0);
}

// ======================= prep kernels ======================================
// Weight layouts: flat[(kq*N + n)*4 + j] packs f16 pair k = 8*kq+2*j of row n.
__global__ __launch_bounds__(256) void prep_w(
    const float* __restrict__ Win, const float* __restrict__ Whh,
    const float* __restrict__ Wout, const float* __restrict__ Wih,
    unsigned* __restrict__ WALLT, unsigned* __restrict__ WCT,
    unsigned* __restrict__ WIT)
{
  int t = blockIdx.x * 256 + threadIdx.x;   // 1,179,648 total u32s
  if (t < 655360) {                          // WALLT: N=2560
    int kq = t / 10240, rem = t - kq * 10240;
    int n = rem >> 2, j = rem & 3;
    int k = 8*kq + 2*j;
    float a, b;
    if (n < 512)       { a = Win[n*512 + k];        b = Win[n*512 + k + 1]; }
    else if (n < 2048) { a = Whh[(n-512)*512 + k];  b = Whh[(n-512)*512 + k + 1]; }
    else               { a = Wout[(size_t)(n-2048)*1024 + 512 + k];
                         b = Wout[(size_t)(n-2048)*1024 + 513 + k]; }
    WALLT[t] = pack_h2(a, b);
  } else if (t < 786432) {                   // WCT: N=512
    int u = t - 655360;
    int kq = u / 2048, rem = u - kq * 2048;
    int n = rem >> 2, j = rem & 3;
    int k = 8*kq + 2*j;
    WCT[u] = pack_h2(Wout[(size_t)n*1024 + k], Wout[(size_t)n*1024 + k + 1]);
  } else {                                   // WIT: N=1536
    int u = t - 786432;
    int kq = u / 6144, rem = u - kq * 6144;
    int n = rem >> 2, j = rem & 3;
    int k = 8*kq + 2*j;
    WIT[u] = pack_h2(Wih[n*512 + k], Wih[n*512 + k + 1]);
  }
}

__global__ __launch_bounds__(256) void lengths_kernel(
    const int* __restrict__ cpt, int* __restrict__ len)
{
  int r = blockIdx.x * 256 + threadIdx.x;
  if (r < 1536) {
    int c = 0;
    for (int s = 0; s < 64; ++s) c += (cpt[r*64 + s] != 0);
    len[r] = c > 1 ? c : 1;
  }
}

// ---- embed GEMM: mem[sent][b][s][h] = f16(elu(emb_table[cpt]@W_eh^T + b)) ----
__global__ __launch_bounds__(256) void embed_gemm(
    const int* __restrict__ cpt, const float* __restrict__ table,
    const float* __restrict__ Weh, const float* __restrict__ beh,
    f16* __restrict__ mem)
{
  __shared__ unsigned short A_lds[64][40];
  __shared__ unsigned short B_lds[64][40];
  const int bid = blockIdx.x;
  const int M0 = (bid >> 3) * 64;
  const int N0 = (bid & 7) * 64;
  const int tid = threadIdx.x, lane = tid & 63, w = tid >> 6;
  const int l15 = lane & 15, quad = lane >> 4;
  const int srow = tid >> 2;
  const int koff = (tid & 3) * 8;
  const int tok = cpt[M0 + srow];
  const float* arow = table + (size_t)tok * 512;
  const float* brow = Weh + (size_t)(N0 + srow) * 512;

  f32x4 acc0 = {0,0,0,0}, acc1 = {0,0,0,0}, acc2 = {0,0,0,0}, acc3 = {0,0,0,0};
  for (int kt = 0; kt < 16; ++kt) {
    const int k0 = kt * 32;
    float4 alo = *(const float4*)(arow + k0 + koff);
    float4 ahi = *(const float4*)(arow + k0 + koff + 4);
    float4 blo = *(const float4*)(brow + k0 + koff);
    float4 bhi = *(const float4*)(brow + k0 + koff + 4);
    __syncthreads();
    *(bf16x8*)(&A_lds[srow][koff]) = cvt8(alo, ahi);
    *(bf16x8*)(&B_lds[srow][koff]) = cvt8(blo, bhi);
    __syncthreads();
    const int kq = quad * 8;
    bf16x8 bfr = *(const bf16x8*)(&B_lds[16*w + l15][kq]);
    bf16x8 a0 = *(const bf16x8*)(&A_lds[l15][kq]);
    bf16x8 a1 = *(const bf16x8*)(&A_lds[16 + l15][kq]);
    bf16x8 a2 = *(const bf16x8*)(&A_lds[32 + l15][kq]);
    bf16x8 a3 = *(const bf16x8*)(&A_lds[48 + l15][kq]);
    acc0 = MFMA16(a0, bfr, acc0);
    acc1 = MFMA16(a1, bfr, acc1);
    acc2 = MFMA16(a2, bfr, acc2);
    acc3 = MFMA16(a3, bfr, acc3);
  }
  const int n = N0 + 16*w + l15;
  const float bias = beh[n];
  f32x4 accs[4] = {acc0, acc1, acc2, acc3};
  #pragma unroll
  for (int mt = 0; mt < 4; ++mt) {
    #pragma unroll
    for (int r = 0; r < 4; ++r) {
      int m = M0 + mt*16 + quad*4 + r;
      float v = accs[mt][r] + bias;
      v = v > 0.f ? v : expm1f(v);
      int s = m & 63, nrow = m >> 6;
      int sent = nrow % 48, b = nrow / 48;
      mem[(((size_t)(sent*32 + b))*64 + s)*512 + n] = (f16)v;
    }
  }
}

// ======================= barrier-free per-batch scan ========================
__global__ __launch_bounds__(512, 1) void scan_local(
    const f16* __restrict__ mem, const int* __restrict__ len,
    const unsigned* __restrict__ WALLT, const unsigned* __restrict__ WCT,
    const unsigned* __restrict__ WIT,
    const float* __restrict__ b_ih, const float* __restrict__ b_hh,
    const float* __restrict__ h0, float* __restrict__ out)
{
  __shared__ __align__(16) f16 mem_s[64][520];     // 1040 B rows
  __shared__ __align__(16) unsigned qh[256];
  __shared__ __align__(16) f16 c2h[512];
  __shared__ __align__(16) f16 x2h[512];
  __shared__ __align__(16) f16 h2h[512];
  __shared__ float hf[512];
  __shared__ float z[2560];
  __shared__ float sc[64], al[64];
  __shared__ float bih_s[1536], bhh_s[1536];

  const int g = blockIdx.x, tid = threadIdx.x;
  const int lane = tid & 63, wv = tid >> 6;
  const unsigned* h2u = (const unsigned*)h2h;
  const unsigned* c2u = (const unsigned*)c2h;
  const unsigned* x2u = (const unsigned*)x2h;

  #pragma unroll
  for (int it = 0; it < 3; ++it) {
    int idx = tid + 512*it;
    bih_s[idx] = b_ih[idx];
    bhh_s[idx] = b_hh[idx];
  }
  { float v = h0[tid]; hf[tid] = v; h2h[tid] = (f16)v; }
  __syncthreads();

  for (int i = 0; i < 48; ++i) {
    const int L = len[g*48 + i];
    // ---- (0) async-stage mem slice via global_load_lds (no data VGPRs) ----
    {
      const f16* src = mem + ((size_t)(i*32 + g)) * 64 * 512;
      #pragma unroll
      for (int r = 0; r < 8; ++r) {
        int s = wv*8 + r;
        load_lds16(src + (size_t)s*512 + lane*8, &mem_s[s][lane*8]);
      }
    }
    // ---- (1) S1: z/q = [W_in; W_hh; Wh2] . h (4-kq chunks, double-buffer) --
    {
      float a0=0.f, a1=0.f, a2=0.f, a3=0.f, a4=0.f;
      uint4 wb[2][20];
      #pragma unroll
      for (int kk = 0; kk < 4; ++kk)
        #pragma unroll
        for (int j = 0; j < 5; ++j)
          wb[0][kk*5+j] = *(const uint4*)(WALLT + ((size_t)kk*2560 + tid + 512*j)*4);
      #pragma unroll
      for (int c = 0; c < 16; ++c) {
        if (c < 15) {
          #pragma unroll
          for (int kk = 0; kk < 4; ++kk)
            #pragma unroll
            for (int j = 0; j < 5; ++j)
              wb[(c+1)&1][kk*5+j] =
                *(const uint4*)(WALLT + ((size_t)((c+1)*4+kk)*2560 + tid + 512*j)*4);
        }
        #pragma unroll
        for (int kk = 0; kk < 4; ++kk) {
          uint4 h4 = *(const uint4*)(h2u + (c*4+kk)*4);
          const uint4* wr = &wb[c&1][kk*5];
          a0 = dot2(wr[0].x, h4.x, a0); a0 = dot2(wr[0].y, h4.y, a0);
          a0 = dot2(wr[0].z, h4.z, a0); a0 = dot2(wr[0].w, h4.w, a0);
          a1 = dot2(wr[1].x, h4.x, a1); a1 = dot2(wr[1].y, h4.y, a1);
          a1 = dot2(wr[1].z, h4.z, a1); a1 = dot2(wr[1].w, h4.w, a1);
          a2 = dot2(wr[2].x, h4.x, a2); a2 = dot2(wr[2].y, h4.y, a2);
          a2 = dot2(wr[2].z, h4.z, a2); a2 = dot2(wr[2].w, h4.w, a2);
          a3 = dot2(wr[3].x, h4.x, a3); a3 = dot2(wr[3].y, h4.y, a3);
          a3 = dot2(wr[3].z, h4.z, a3); a3 = dot2(wr[3].w, h4.w, a3);
          a4 = dot2(wr[4].x, h4.x, a4); a4 = dot2(wr[4].y, h4.y, a4);
          a4 = dot2(wr[4].z, h4.z, a4); a4 = dot2(wr[4].w, h4.w, a4);
        }
      }
      { f16 qv = (f16)a0;
        *((unsigned short*)qh + tid) = __builtin_bit_cast(unsigned short, qv); }
      z[tid + 512]  = a1;
      z[tid + 1024] = a2;
      z[tid + 1536] = a3;
      z[tid + 2048] = a4;
    }
    __syncthreads();   // drains global_load_lds too: mem_s ready

    // ---- (2) scores + softmax --------------------------------------------
    {
      const int s = tid >> 3, p = tid & 7;
      const unsigned* mrow = (const unsigned*)(&mem_s[s][0]) + p*32;
      const unsigned* qrow = qh + p*32;
      float sum = 0.f;
      #pragma unroll
      for (int k = 0; k < 32; ++k) sum = dot2(mrow[k], qrow[k], sum);
      sum += __shfl_xor(sum, 1);
      sum += __shfl_xor(sum, 2);
      sum += __shfl_xor(sum, 4);
      if (p == 0) sc[s] = (s < L) ? sum : -1e30f;
    }
    __syncthreads();
    if (tid < 64) {
      float v = sc[tid];
      float mx = v;
      #pragma unroll
      for (int o = 32; o; o >>= 1) mx = fmaxf(mx, __shfl_xor(mx, o));
      float e = __expf(v - mx);
      float sm = e;
      #pragma unroll
      for (int o = 32; o; o >>= 1) sm += __shfl_xor(sm, o);
      al[tid] = e * __builtin_amdgcn_rcpf(sm);
    }
    __syncthreads();

    // ---- (3) context c[d] = sum_s al[s]*mem_s[s][d] ------------------------
    {
      float cacc = 0.f;
      #pragma unroll 8
      for (int s = 0; s < 64; ++s) cacc += al[s] * (float)mem_s[s][tid];
      c2h[tid] = (f16)cacc;
    }
    __syncthreads();

    // ---- (4) x[n] = tanh(c.WC[n] + hw2[n]) (8-kq chunks, double-buffer) ----
    {
      float acc = z[2048 + tid];
      uint4 wb[2][8];
      #pragma unroll
      for (int kk = 0; kk < 8; ++kk)
        wb[0][kk] = *(const uint4*)(WCT + ((size_t)kk*512 + tid)*4);
      #pragma unroll
      for (int c = 0; c < 8; ++c) {
        if (c < 7) {
          #pragma unroll
          for (int kk = 0; kk < 8; ++kk)
            wb[(c+1)&1][kk] = *(const uint4*)(WCT + ((size_t)((c+1)*8+kk)*512 + tid)*4);
        }
        #pragma unroll
        for (int kk = 0; kk < 8; ++kk) {
          uint4 c4 = *(const uint4*)(c2u + (c*8+kk)*4);
          uint4 w = wb[c&1][kk];
          acc = dot2(w.x, c4.x, acc);
          acc = dot2(w.y, c4.y, acc);
          acc = dot2(w.z, c4.z, acc);
          acc = dot2(w.w, c4.w, acc);
        }
      }
      x2h[tid] = (f16)ftanh(acc);
    }
    __syncthreads();

    // ---- (5) gi = x.W_ih^T (3 gates; 4-kq chunks, double-buffer) + GRU -----
    {
      float a0 = 0.f, a1 = 0.f, a2 = 0.f;
      uint4 wb[2][12];
      #pragma unroll
      for (int kk = 0; kk < 4; ++kk)
        #pragma unroll
        for (int j = 0; j < 3; ++j)
          wb[0][kk*3+j] = *(const uint4*)(WIT + ((size_t)kk*1536 + tid + 512*j)*4);
      #pragma unroll
      for (int c = 0; c < 16; ++c) {
        if (c < 15) {
          #pragma unroll
          for (int kk = 0; kk < 4; ++kk)
            #pragma unroll
            for (int j = 0; j < 3; ++j)
              wb[(c+1)&1][kk*3+j] =
                *(const uint4*)(WIT + ((size_t)((c+1)*4+kk)*1536 + tid + 512*j)*4);
        }
        #pragma unroll
        for (int kk = 0; kk < 4; ++kk) {
          uint4 x4 = *(const uint4*)(x2u + (c*4+kk)*4);
          const uint4* wr = &wb[c&1][kk*3];
          a0 = dot2(wr[0].x, x4.x, a0); a0 = dot2(wr[0].y, x4.y, a0);
          a0 = dot2(wr[0].z, x4.z, a0); a0 = dot2(wr[0].w, x4.w, a0);
          a1 = dot2(wr[1].x, x4.x, a1); a1 = dot2(wr[1].y, x4.y, a1);
          a1 = dot2(wr[1].z, x4.z, a1); a1 = dot2(wr[1].w, x4.w, a1);
          a2 = dot2(wr[2].x, x4.x, a2); a2 = dot2(wr[2].y, x4.y, a2);
          a2 = dot2(wr[2].z, x4.z, a2); a2 = dot2(wr[2].w, x4.w, a2);
        }
      }
      const int d = tid;
      float ir = a0 + bih_s[d];
      float iz = a1 + bih_s[512 + d];
      float in = a2 + bih_s[1024 + d];
      float hr = z[512 + d]  + bhh_s[d];
      float hz = z[1024 + d] + bhh_s[512 + d];
      float hn = z[1536 + d] + bhh_s[1024 + d];
      float ho = hf[d];
      float rr = fsig(ir + hr);
      float zz = fsig(iz + hz);
      float nn = ftanh(in + rr * hn);
      float res = (1.f - zz) * nn + zz * ho;
      if (i == 47) {
        out[g*512 + d] = res;
      } else {
        hf[d] = res;
        h2h[d] = (f16)res;
      }
    }
    __syncthreads();
  }
}

// ---------------------------------------------------------------------------
extern "C" void kernel_launch(void* const* d_in, const int* in_sizes, int n_in,
                              void* d_out, int out_size, void* d_ws, size_t ws_size,
                              hipStream_t stream) {
  const int*   cpt   = (const int*)d_in[0];
  const float* table = (const float*)d_in[2];
  const float* Weh   = (const float*)d_in[3];
  const float* beh   = (const float*)d_in[4];
  const float* h0    = (const float*)d_in[5];
  const float* Win   = (const float*)d_in[6];
  const float* Wout  = (const float*)d_in[7];
  const float* Wih   = (const float*)d_in[8];
  const float* Whh   = (const float*)d_in[9];
  const float* bih   = (const float*)d_in[10];
  const float* bhh   = (const float*)d_in[11];

  if (ws_size < WS_NEED) return;

  char* ws = (char*)d_ws;
  f16*      mem   = (f16*)(ws + OFF_MEM);
  unsigned* WALLT = (unsigned*)(ws + OFF_WALLT);
  unsigned* WCT   = (unsigned*)(ws + OFF_WCT);
  unsigned* WIT   = (unsigned*)(ws + OFF_WIT);
  int*      len   = (int*)(ws + OFF_LEN);

  prep_w<<<4608, 256, 0, stream>>>(Win, Whh, Wout, Wih, WALLT, WCT, WIT);
  lengths_kernel<<<6, 256, 0, stream>>>(cpt, len);
  embed_gemm<<<12288, 256, 0, stream>>>(cpt, table, Weh, beh, mem);
  scan_local<<<32, 512, 0, stream>>>(mem, len, WALLT, WCT, WIT,
                                     bih, bhh, h0, (float*)d_out);
}

// Round 7
// 4372.444 us; speedup vs baseline: 2.0219x; 2.0219x over previous
//
#include <hip/hip_runtime.h>
#include <hip/hip_bf16.h>
#include <stdint.h>

// ---------------------------------------------------------------------------
// GraphEncoder. Round 7: k=8 slice-split scan. 256 blocks x 512 threads;
// block (g,j) owns batch g, output-dim slice j (64 dims). Weight bytes per
// block per step drop 4.7 MB -> 1.09 MB (the R5/R6 per-CU bandwidth wall).
// Only 2 group-of-8 flag syncs per step (x exchange, h exchange); scores/
// softmax/c are replicated to avoid a third sync. Prefetch depth 2 only
// (R6 lesson: deep register buffers spill to scratch).
// ---------------------------------------------------------------------------

typedef __bf16 bf16_t;
typedef __bf16 bf16x8 __attribute__((ext_vector_type(8)));
typedef float  f32x4  __attribute__((ext_vector_type(4)));
typedef _Float16 f16;
typedef _Float16 f16x2 __attribute__((ext_vector_type(2)));

#define MFMA16(a,b,c) __builtin_amdgcn_mfma_f32_16x16x32_bf16((a),(b),(c),0,0,0)

// ---- workspace layout (bytes) ----
static constexpr size_t OFF_MEM   = 0;                      // f16 [1536][64][512]
static constexpr size_t OFF_WALLT = 100663296;              // u32 [64][2560][4]
static constexpr size_t OFF_WCT   = OFF_WALLT + 2621440;    // u32 [64][512][4]
static constexpr size_t OFF_WIT   = OFF_WCT + 524288;       // u32 [64][1536][4]
static constexpr size_t OFF_LEN   = OFF_WIT + 1572864;      // int [1536]
static constexpr size_t OFF_XG    = OFF_LEN + 8192;         // u32 [32][256] x f16-pairs
static constexpr size_t OFF_HGH   = OFF_XG + 32768;         // u32 [32][256] h f16-pairs
static constexpr size_t OFF_FLG   = OFF_HGH + 32768;        // u32 [32][16]
static constexpr size_t WS_NEED   = OFF_FLG + 2048;         // 105,457,664

// ---- helpers ----
__device__ __forceinline__ unsigned ld_a32(const void* p) {
  return __hip_atomic_load((const unsigned*)p, __ATOMIC_RELAXED, __HIP_MEMORY_SCOPE_AGENT);
}
__device__ __forceinline__ void st_a32(void* p, unsigned v) {
  __hip_atomic_store((unsigned*)p, v, __ATOMIC_RELAXED, __HIP_MEMORY_SCOPE_AGENT);
}
__device__ __forceinline__ float dot2(unsigned w, unsigned x, float acc) {
#if __has_builtin(__builtin_amdgcn_fdot2)
  return __builtin_amdgcn_fdot2(__builtin_bit_cast(f16x2, w),
                                __builtin_bit_cast(f16x2, x), acc, false);
#else
  f16x2 wv = __builtin_bit_cast(f16x2, w);
  f16x2 xv = __builtin_bit_cast(f16x2, x);
  return acc + (float)wv[0]*(float)xv[0] + (float)wv[1]*(float)xv[1];
#endif
}
__device__ __forceinline__ unsigned pack_h2(float a, float b) {
  f16 ha = (f16)a, hb = (f16)b;
  unsigned short ua = __builtin_bit_cast(unsigned short, ha);
  unsigned short ub = __builtin_bit_cast(unsigned short, hb);
  return (unsigned)ua | ((unsigned)ub << 16);
}
__device__ __forceinline__ bf16x8 cvt8(float4 lo, float4 hi) {
  bf16x8 v;
  v[0]=(__bf16)lo.x; v[1]=(__bf16)lo.y; v[2]=(__bf16)lo.z; v[3]=(__bf16)lo.w;
  v[4]=(__bf16)hi.x; v[5]=(__bf16)hi.y; v[6]=(__bf16)hi.z; v[7]=(__bf16)hi.w;
  return v;
}
__device__ __forceinline__ float fsig(float x) {
  return __builtin_amdgcn_rcpf(1.f + __expf(-x));
}
__device__ __forceinline__ float ftanh(float x) {
  float e = __expf(-2.f * fabsf(x));
  float t = (1.f - e) * __builtin_amdgcn_rcpf(1.f + e);
  return __builtin_copysignf(t, x);
}
__device__ __forceinline__ void load_lds16(const f16* g, f16* l) {
  __builtin_amdgcn_global_load_lds(
      (const __attribute__((address_space(1))) unsigned*)g,
      (__attribute__((address_space(3))) unsigned*)l, 16, 0, 0);
}

// ======================= prep kernels (unchanged from R5) ===================
__global__ __launch_bounds__(256) void prep_w(
    const float* __restrict__ Win, const float* __restrict__ Whh,
    const float* __restrict__ Wout, const float* __restrict__ Wih,
    unsigned* __restrict__ WALLT, unsigned* __restrict__ WCT,
    unsigned* __restrict__ WIT)
{
  int t = blockIdx.x * 256 + threadIdx.x;   // 1,179,648 total u32s
  if (t < 655360) {                          // WALLT: N=2560
    int kq = t / 10240, rem = t - kq * 10240;
    int n = rem >> 2, j = rem & 3;
    int k = 8*kq + 2*j;
    float a, b;
    if (n < 512)       { a = Win[n*512 + k];        b = Win[n*512 + k + 1]; }
    else if (n < 2048) { a = Whh[(n-512)*512 + k];  b = Whh[(n-512)*512 + k + 1]; }
    else               { a = Wout[(size_t)(n-2048)*1024 + 512 + k];
                         b = Wout[(size_t)(n-2048)*1024 + 513 + k]; }
    WALLT[t] = pack_h2(a, b);
  } else if (t < 786432) {                   // WCT: N=512
    int u = t - 655360;
    int kq = u / 2048, rem = u - kq * 2048;
    int n = rem >> 2, j = rem & 3;
    int k = 8*kq + 2*j;
    WCT[u] = pack_h2(Wout[(size_t)n*1024 + k], Wout[(size_t)n*1024 + k + 1]);
  } else {                                   // WIT: N=1536
    int u = t - 786432;
    int kq = u / 6144, rem = u - kq * 6144;
    int n = rem >> 2, j = rem & 3;
    int k = 8*kq + 2*j;
    WIT[u] = pack_h2(Wih[n*512 + k], Wih[n*512 + k + 1]);
  }
}

__global__ __launch_bounds__(256) void lengths_kernel(
    const int* __restrict__ cpt, int* __restrict__ len)
{
  int r = blockIdx.x * 256 + threadIdx.x;
  if (r < 1536) {
    int c = 0;
    for (int s = 0; s < 64; ++s) c += (cpt[r*64 + s] != 0);
    len[r] = c > 1 ? c : 1;
  }
}

__global__ __launch_bounds__(256) void embed_gemm(
    const int* __restrict__ cpt, const float* __restrict__ table,
    const float* __restrict__ Weh, const float* __restrict__ beh,
    f16* __restrict__ mem)
{
  __shared__ unsigned short A_lds[64][40];
  __shared__ unsigned short B_lds[64][40];
  const int bid = blockIdx.x;
  const int M0 = (bid >> 3) * 64;
  const int N0 = (bid & 7) * 64;
  const int tid = threadIdx.x, lane = tid & 63, w = tid >> 6;
  const int l15 = lane & 15, quad = lane >> 4;
  const int srow = tid >> 2;
  const int koff = (tid & 3) * 8;
  const int tok = cpt[M0 + srow];
  const float* arow = table + (size_t)tok * 512;
  const float* brow = Weh + (size_t)(N0 + srow) * 512;

  f32x4 acc0 = {0,0,0,0}, acc1 = {0,0,0,0}, acc2 = {0,0,0,0}, acc3 = {0,0,0,0};
  for (int kt = 0; kt < 16; ++kt) {
    const int k0 = kt * 32;
    float4 alo = *(const float4*)(arow + k0 + koff);
    float4 ahi = *(const float4*)(arow + k0 + koff + 4);
    float4 blo = *(const float4*)(brow + k0 + koff);
    float4 bhi = *(const float4*)(brow + k0 + koff + 4);
    __syncthreads();
    *(bf16x8*)(&A_lds[srow][koff]) = cvt8(alo, ahi);
    *(bf16x8*)(&B_lds[srow][koff]) = cvt8(blo, bhi);
    __syncthreads();
    const int kq = quad * 8;
    bf16x8 bfr = *(const bf16x8*)(&B_lds[16*w + l15][kq]);
    bf16x8 a0 = *(const bf16x8*)(&A_lds[l15][kq]);
    bf16x8 a1 = *(const bf16x8*)(&A_lds[16 + l15][kq]);
    bf16x8 a2 = *(const bf16x8*)(&A_lds[32 + l15][kq]);
    bf16x8 a3 = *(const bf16x8*)(&A_lds[48 + l15][kq]);
    acc0 = MFMA16(a0, bfr, acc0);
    acc1 = MFMA16(a1, bfr, acc1);
    acc2 = MFMA16(a2, bfr, acc2);
    acc3 = MFMA16(a3, bfr, acc3);
  }
  const int n = N0 + 16*w + l15;
  const float bias = beh[n];
  f32x4 accs[4] = {acc0, acc1, acc2, acc3};
  #pragma unroll
  for (int mt = 0; mt < 4; ++mt) {
    #pragma unroll
    for (int r = 0; r < 4; ++r) {
      int m = M0 + mt*16 + quad*4 + r;
      float v = accs[mt][r] + bias;
      v = v > 0.f ? v : expm1f(v);
      int s = m & 63, nrow = m >> 6;
      int sent = nrow % 48, b = nrow / 48;
      mem[(((size_t)(sent*32 + b))*64 + s)*512 + n] = (f16)v;
    }
  }
}

// ======================= k=8 slice-split scan ==============================
__global__ __launch_bounds__(512, 1) void scan_split(
    const f16* __restrict__ mem, const int* __restrict__ len,
    const unsigned* __restrict__ WALLT, const unsigned* __restrict__ WCT,
    const unsigned* __restrict__ WIT,
    const float* __restrict__ b_ih, const float* __restrict__ b_hh,
    const float* __restrict__ h0,
    unsigned* __restrict__ xg, unsigned* __restrict__ hgh,
    unsigned* __restrict__ flags, float* __restrict__ out)
{
  __shared__ __align__(16) f16 mem_s[64][520];   // 66,560 B
  __shared__ __align__(16) unsigned qh[256];      // q  (f16 pairs)
  __shared__ __align__(16) unsigned h2u[256];     // h  (f16 pairs)
  __shared__ __align__(16) unsigned c2u[256];     // c  (f16 pairs)
  __shared__ __align__(16) unsigned x2u[256];     // x  (f16 pairs)
  __shared__ float ghs[192];                      // gh slice (+b_hh)
  __shared__ float hw2s[64];                      // hw2 slice
  __shared__ float gi_s[192];                     // gi slice
  __shared__ float hsl[64];                       // h f32 slice (block-local!)
  __shared__ float sc[64], al[64];
  __shared__ float bih_s[192];

  const int bid = blockIdx.x, g = bid >> 3, j = bid & 7;
  const int tid = threadIdx.x, lane = tid & 63, wv = tid >> 6;

  // ---- static per-thread row indices ----
  const int row_q = tid;                          // WALLT q row
  int row_e = row_q;                              // extra row (tid<256)
  if (tid < 64)        row_e = 512 + 64*j + tid;           // W_hh r-gate
  else if (tid < 128)  row_e = 1024 + 64*j + (tid - 64);   // W_hh z-gate
  else if (tid < 192)  row_e = 1536 + 64*j + (tid - 128);  // W_hh n-gate
  else if (tid < 256)  row_e = 2048 + 64*j + (tid - 192);  // Wh2
  // gi rows: r = tid>>1 (<192), gate = r>>6
  const int r_gi = (tid >> 1) < 192 ? (tid >> 1) : 0;
  const int row_gi = (r_gi >> 6)*512 + 64*j + (r_gi & 63);
  // x rows: r = tid>>3 (<64)
  const int r_x = tid >> 3, p_x = tid & 7;
  const int row_x = 64*j + r_x;

  // ---- prologue ----
  if (tid < 64) hsl[tid] = h0[64*j + tid];
  if (tid < 256) h2u[tid] = pack_h2(h0[2*tid], h0[2*tid + 1]);
  if (tid < 192) {
    int gate = tid >> 6, dd = tid & 63;
    bih_s[tid] = b_ih[gate*512 + 64*j + dd];
    // ghs gets b_hh added each step in S1; preload into register-less LDS? read each step instead:
  }
  __syncthreads();

  for (int i = 0; i < 48; ++i) {
    // ---- (0) async-stage mem slice (64 KB) -------------------------------
    {
      const f16* src = mem + ((size_t)(i*32 + g)) * 64 * 512;
      #pragma unroll
      for (int r = 0; r < 8; ++r) {
        int s = wv*8 + r;
        load_lds16(src + (size_t)s*512 + lane*8, &mem_s[s][lane*8]);
      }
    }
    // ---- (1) S1: q full (replicated) + gh/hw2 slice ----------------------
    {
      float aq = 0.f, ae = 0.f;
      uint4 bq[2], be[2];
      bq[0] = *(const uint4*)(WALLT + ((size_t)0*2560 + row_q)*4);
      be[0] = *(const uint4*)(WALLT + ((size_t)0*2560 + row_e)*4);
      #pragma unroll
      for (int kq = 0; kq < 64; ++kq) {
        const int cur = kq & 1, nxt = cur ^ 1;
        if (kq < 63) {
          bq[nxt] = *(const uint4*)(WALLT + ((size_t)(kq+1)*2560 + row_q)*4);
          be[nxt] = *(const uint4*)(WALLT + ((size_t)(kq+1)*2560 + row_e)*4);
        }
        uint4 h4 = *(const uint4*)(h2u + kq*4);
        aq = dot2(bq[cur].x, h4.x, aq); aq = dot2(bq[cur].y, h4.y, aq);
        aq = dot2(bq[cur].z, h4.z, aq); aq = dot2(bq[cur].w, h4.w, aq);
        ae = dot2(be[cur].x, h4.x, ae); ae = dot2(be[cur].y, h4.y, ae);
        ae = dot2(be[cur].z, h4.z, ae); ae = dot2(be[cur].w, h4.w, ae);
      }
      { f16 qv = (f16)aq;
        ((unsigned short*)qh)[tid] = __builtin_bit_cast(unsigned short, qv); }
      if (tid < 192) {
        int gate = tid >> 6, dd = tid & 63;
        ghs[tid] = ae + b_hh[gate*512 + 64*j + dd];
      } else if (tid < 256) {
        hw2s[tid - 192] = ae;
      }
    }
    __syncthreads();   // drains global_load_lds: mem_s ready

    // ---- (2) scores + mask ----------------------------------------------
    {
      const int s = tid >> 3, p = tid & 7;
      const unsigned* mrow = (const unsigned*)(&mem_s[s][0]) + p*32;
      const unsigned* qrow = qh + p*32;
      float sum = 0.f;
      #pragma unroll
      for (int k = 0; k < 32; ++k) sum = dot2(mrow[k], qrow[k], sum);
      sum += __shfl_xor(sum, 1);
      sum += __shfl_xor(sum, 2);
      sum += __shfl_xor(sum, 4);
      if (p == 0) {
        int L = len[g*48 + i];
        sc[s] = (s < L) ? sum : -1e30f;
      }
    }
    __syncthreads();
    // ---- (3) softmax (replicated on first 64 threads) --------------------
    if (tid < 64) {
      float v = sc[tid];
      float mx = v;
      #pragma unroll
      for (int o = 32; o; o >>= 1) mx = fmaxf(mx, __shfl_xor(mx, o));
      float e = __expf(v - mx);
      float sm = e;
      #pragma unroll
      for (int o = 32; o; o >>= 1) sm += __shfl_xor(sm, o);
      al[tid] = e * __builtin_amdgcn_rcpf(sm);
    }
    __syncthreads();
    // ---- (4) context c (replicated) --------------------------------------
    {
      float cacc = 0.f;
      #pragma unroll 8
      for (int s = 0; s < 64; ++s) cacc += al[s] * (float)mem_s[s][tid];
      float cp = __shfl_down(cacc, 1);
      if ((tid & 1) == 0) c2u[tid >> 1] = pack_h2(cacc, cp);
    }
    __syncthreads();
    // ---- (5) x slice: x_n = tanh(c.Wc_n + hw2_n), n in [64j,64j+64) ------
    {
      float acc = 0.f;
      uint4 wb[2];
      wb[0] = *(const uint4*)(WCT + ((size_t)(p_x*8)*512 + row_x)*4);
      #pragma unroll
      for (int kb = 0; kb < 8; ++kb) {
        const int cur = kb & 1, nxt = cur ^ 1;
        if (kb < 7)
          wb[nxt] = *(const uint4*)(WCT + ((size_t)(p_x*8+kb+1)*512 + row_x)*4);
        uint4 c4 = *(const uint4*)(c2u + (p_x*8+kb)*4);
        acc = dot2(wb[cur].x, c4.x, acc); acc = dot2(wb[cur].y, c4.y, acc);
        acc = dot2(wb[cur].z, c4.z, acc); acc = dot2(wb[cur].w, c4.w, acc);
      }
      acc += __shfl_xor(acc, 1);
      acc += __shfl_xor(acc, 2);
      acc += __shfl_xor(acc, 4);
      float xv = ftanh(acc + hw2s[r_x]);
      float xp = __shfl_down(xv, 8);     // x of r_x+1
      if ((tid & 15) == 0)
        st_a32(xg + g*256 + 32*j + (r_x >> 1), pack_h2(xv, xp));
    }
    // ---- SYNC A: x exchange within group ---------------------------------
    __syncthreads();                      // drain xg stores
    {
      const unsigned tgt = 2*(unsigned)i + 1;
      if (tid == 0) st_a32(flags + g*16 + j, tgt);
      if (tid < 64) {
        unsigned long long done;
        do {
          unsigned f = ld_a32(flags + g*16 + (tid & 7));
          done = __ballot(f >= tgt);
          if (done != ~0ull) __builtin_amdgcn_s_sleep(1);
        } while (done != ~0ull);
      }
    }
    __syncthreads();
    if (tid < 256) x2u[tid] = ld_a32(xg + g*256 + tid);
    __syncthreads();
    // ---- (6) gi slice: 192 rows, (r,p) = (tid>>1, tid&1), K halves -------
    if (tid < 384) {
      float acc = 0.f;
      const int p = tid & 1;
      uint4 wb[2];
      wb[0] = *(const uint4*)(WIT + ((size_t)(p*32)*1536 + row_gi)*4);
      #pragma unroll
      for (int kb = 0; kb < 32; ++kb) {
        const int cur = kb & 1, nxt = cur ^ 1;
        if (kb < 31)
          wb[nxt] = *(const uint4*)(WIT + ((size_t)(p*32+kb+1)*1536 + row_gi)*4);
        uint4 x4 = *(const uint4*)(x2u + (p*32+kb)*4);
        acc = dot2(wb[cur].x, x4.x, acc); acc = dot2(wb[cur].y, x4.y, acc);
        acc = dot2(wb[cur].z, x4.z, acc); acc = dot2(wb[cur].w, x4.w, acc);
      }
      acc += __shfl_xor(acc, 1);
      if (p == 0) gi_s[r_gi] = acc;
    }
    __syncthreads();
    // ---- (7) GRU update for d-slice --------------------------------------
    if (tid < 64) {
      const int d = tid, D = 64*j + d;
      float ir = gi_s[d]        + bih_s[d];
      float iz = gi_s[64 + d]   + bih_s[64 + d];
      float in = gi_s[128 + d]  + bih_s[128 + d];
      float hr = ghs[d], hz = ghs[64 + d], hn = ghs[128 + d];
      float ho = hsl[d];
      float rr = fsig(ir + hr);
      float zz = fsig(iz + hz);
      float nn = ftanh(in + rr * hn);
      float res = (1.f - zz) * nn + zz * ho;
      if (i == 47) {
        out[g*512 + D] = res;
      } else {
        hsl[d] = res;
        float r2 = __shfl_down(res, 1);
        if ((d & 1) == 0)
          st_a32(hgh + g*256 + 32*j + (d >> 1), pack_h2(res, r2));
      }
    }
    if (i == 47) break;
    // ---- SYNC B: h exchange within group ---------------------------------
    __syncthreads();                      // drain hgh stores
    {
      const unsigned tgt = 2*(unsigned)i + 2;
      if (tid == 0) st_a32(flags + g*16 + j, tgt);
      if (tid < 64) {
        unsigned long long done;
        do {
          unsigned f = ld_a32(flags + g*16 + (tid & 7));
          done = __ballot(f >= tgt);
          if (done != ~0ull) __builtin_amdgcn_s_sleep(1);
        } while (done != ~0ull);
      }
    }
    __syncthreads();
    if (tid < 256) h2u[tid] = ld_a32(hgh + g*256 + tid);
    __syncthreads();
  }
}

// ---------------------------------------------------------------------------
extern "C" void kernel_launch(void* const* d_in, const int* in_sizes, int n_in,
                              void* d_out, int out_size, void* d_ws, size_t ws_size,
                              hipStream_t stream) {
  const int*   cpt   = (const int*)d_in[0];
  const float* table = (const float*)d_in[2];
  const float* Weh   = (const float*)d_in[3];
  const float* beh   = (const float*)d_in[4];
  const float* h0    = (const float*)d_in[5];
  const float* Win   = (const float*)d_in[6];
  const float* Wout  = (const float*)d_in[7];
  const float* Wih   = (const float*)d_in[8];
  const float* Whh   = (const float*)d_in[9];
  const float* bih   = (const float*)d_in[10];
  const float* bhh   = (const float*)d_in[11];

  if (ws_size < WS_NEED) return;

  char* ws = (char*)d_ws;
  f16*      mem   = (f16*)(ws + OFF_MEM);
  unsigned* WALLT = (unsigned*)(ws + OFF_WALLT);
  unsigned* WCT   = (unsigned*)(ws + OFF_WCT);
  unsigned* WIT   = (unsigned*)(ws + OFF_WIT);
  int*      len   = (int*)(ws + OFF_LEN);
  unsigned* xg    = (unsigned*)(ws + OFF_XG);
  unsigned* hgh   = (unsigned*)(ws + OFF_HGH);
  unsigned* flg   = (unsigned*)(ws + OFF_FLG);

  hipMemsetAsync(flg, 0, 2048, stream);
  prep_w<<<4608, 256, 0, stream>>>(Win, Whh, Wout, Wih, WALLT, WCT, WIT);
  lengths_kernel<<<6, 256, 0, stream>>>(cpt, len);
  embed_gemm<<<12288, 256, 0, stream>>>(cpt, table, Weh, beh, mem);
  scan_split<<<256, 512, 0, stream>>>(mem, len, WALLT, WCT, WIT,
                                      bih, bhh, h0, xg, hgh, flg, (float*)d_out);
}